// Round 2
// baseline (238.298 us; speedup 1.0000x reference)
//
#include <hip/hip_runtime.h>

// GWRouter: x = mean(wm_state [4,4096,2048] f32); sim[e] = -(proto[e]-x)^2;
// probs = softmax(sim); top-2; mask; EMA usage update; balance loss.
// Outputs flat f32: mask[0:16), probs[16:32), balance_loss[32],
// new_usage_ema[33:49), topk_idx[49:51).
//
// Single fused kernel: grid-stride f32x4 streaming reduce -> per-block f64
// partial -> device-scope atomic "last block done" -> last block reduces
// partials + tiny epilogue. Counter zeroed via hipMemsetAsync (graph-safe).

#define NUM_EXPERTS 16
#define RED_BLOCKS 2048
#define RED_THREADS 256

typedef float f32x4 __attribute__((ext_vector_type(4)));

__global__ __launch_bounds__(RED_THREADS)
void gw_router_fused(const f32x4* __restrict__ x4, int n4,
                     const float* __restrict__ prototypes,
                     const float* __restrict__ usage_ema,
                     float* __restrict__ out,
                     double* __restrict__ partials,
                     unsigned int* __restrict__ counter,
                     long long n_total) {
    __shared__ double sdata[RED_THREADS / 64];
    __shared__ int s_is_last;

    const int tid = blockIdx.x * blockDim.x + threadIdx.x;
    const int stride = gridDim.x * blockDim.x;

    // 4 independent f32 accumulators: no f64 latency chain in the load loop.
    float a0 = 0.f, a1 = 0.f, a2 = 0.f, a3 = 0.f;
    const int iters = n4 / stride;
    int i = tid;
    for (int k = 0; k < iters; ++k, i += stride) {
        f32x4 v = __builtin_nontemporal_load(x4 + i);
        a0 += v.x; a1 += v.y; a2 += v.z; a3 += v.w;
    }
    for (; i < n4; i += stride) {  // tail (empty when n4 % stride == 0)
        f32x4 v = __builtin_nontemporal_load(x4 + i);
        a0 += v.x; a1 += v.y; a2 += v.z; a3 += v.w;
    }

    double acc = ((double)a0 + (double)a1) + ((double)a2 + (double)a3);
    #pragma unroll
    for (int off = 32; off > 0; off >>= 1)
        acc += __shfl_down(acc, off, 64);

    const int lane = threadIdx.x & 63;
    const int wave = threadIdx.x >> 6;
    if (lane == 0) sdata[wave] = acc;
    __syncthreads();

    if (threadIdx.x == 0) {
        double s = sdata[0] + sdata[1] + sdata[2] + sdata[3];
        partials[blockIdx.x] = s;
        // acq_rel RMW: releases the partial store (device scope), and for the
        // last arriver acquires the whole release sequence.
        unsigned prev = __hip_atomic_fetch_add(counter, 1u, __ATOMIC_ACQ_REL,
                                               __HIP_MEMORY_SCOPE_AGENT);
        s_is_last = (prev == (unsigned)(gridDim.x - 1)) ? 1 : 0;
    }
    __syncthreads();
    if (!s_is_last) return;

    // ---- last block: final reduction over partials ----
    double facc = 0.0;
    for (int p = threadIdx.x; p < RED_BLOCKS; p += RED_THREADS)
        facc += __hip_atomic_load(&partials[p], __ATOMIC_ACQUIRE,
                                  __HIP_MEMORY_SCOPE_AGENT);
    #pragma unroll
    for (int off = 32; off > 0; off >>= 1)
        facc += __shfl_down(facc, off, 64);
    if (lane == 0) sdata[wave] = facc;
    __syncthreads();

    if (threadIdx.x == 0) {
        const double total = sdata[0] + sdata[1] + sdata[2] + sdata[3];
        const float x = (float)(total / (double)n_total);

        float sim[NUM_EXPERTS];
        float m = -1e30f;
        #pragma unroll
        for (int e = 0; e < NUM_EXPERTS; ++e) {
            float d = prototypes[e] - x;
            sim[e] = -d * d;
            m = fmaxf(m, sim[e]);
        }
        float probs[NUM_EXPERTS];
        float s = 0.0f;
        #pragma unroll
        for (int e = 0; e < NUM_EXPERTS; ++e) {
            probs[e] = expf(sim[e] - m);
            s += probs[e];
        }
        const float inv_s = 1.0f / s;
        #pragma unroll
        for (int e = 0; e < NUM_EXPERTS; ++e) probs[e] *= inv_s;

        // top-2, lowest-index tie-break (matches jax.lax.top_k)
        int i0 = 0;
        #pragma unroll
        for (int e = 1; e < NUM_EXPERTS; ++e)
            if (probs[e] > probs[i0]) i0 = e;
        int i1 = -1;
        #pragma unroll
        for (int e = 0; e < NUM_EXPERTS; ++e) {
            if (e == i0) continue;
            if (i1 < 0 || probs[e] > probs[i1]) i1 = e;
        }

        const float alpha = 1.0f / 1000.0f;
        const float target = 1.0f / (float)NUM_EXPERTS;
        float bal = 0.0f;
        #pragma unroll
        for (int e = 0; e < NUM_EXPERTS; ++e) {
            float mk = (e == i0 || e == i1) ? 1.0f : 0.0f;
            float ne = (1.0f - alpha) * usage_ema[e] + alpha * mk;
            out[e]      = mk;       // mask
            out[16 + e] = probs[e]; // probs
            out[33 + e] = ne;       // new_usage_ema
            float dlt = ne - target;
            bal += dlt * dlt;
        }
        out[32] = (bal / (float)NUM_EXPERTS) * 1e-3f; // balance_loss
        out[49] = (float)i0;                          // topk_idx
        out[50] = (float)i1;
    }
}

extern "C" void kernel_launch(void* const* d_in, const int* in_sizes, int n_in,
                              void* d_out, int out_size, void* d_ws, size_t ws_size,
                              hipStream_t stream) {
    const f32x4* wm_state   = (const f32x4*)d_in[0];
    const float* prototypes = (const float*)d_in[1];
    const float* usage_ema  = (const float*)d_in[2];
    float* out = (float*)d_out;

    const long long n_total = (long long)in_sizes[0];
    const int n4 = (int)(n_total / 4);

    // d_ws layout: [0, 16 KiB) partials (2048 doubles), [16 KiB, +4) counter
    double* partials = (double*)d_ws;
    unsigned int* counter = (unsigned int*)((char*)d_ws + RED_BLOCKS * sizeof(double));

    hipMemsetAsync(counter, 0, sizeof(unsigned int), stream);
    gw_router_fused<<<RED_BLOCKS, RED_THREADS, 0, stream>>>(
        wm_state, n4, prototypes, usage_ema, out, partials, counter, n_total);
}